// Round 6
// baseline (149.802 us; speedup 1.0000x reference)
//
#include <hip/hip_runtime.h>
#include <math.h>

// output offsets (floats)
#define O_TZ1      0
#define O_TZ2      1024
#define O_FWD      2048
#define O_EQUI     18432
#define O_ATTN     18433
#define O_ORTH     35841
#define O_PAR      35842
#define O_COMM     35843
#define O_SPARSE   35844
#define O_SECLOSS  35845
#define O_SUB      35846

// partial-slot layout (floats at ws base)
#define P_SECLOSS  0      // 64
#define P_SPARSE   64     // 256
#define P_PAR      320    // 2176
#define P_ORTH     2496   // 120
#define P_EQUI     2616   // 4
#define P_CPAIR    2620   // 120  (total 2740)

// ---------------- shared device helpers ----------------

__device__ __forceinline__ void block_store(float v, float* red, int t, float* slot, float scale)
{
    red[t] = v;
    __syncthreads();
    for (int off = 128; off > 0; off >>= 1) { if (t < off) red[t] += red[t+off]; __syncthreads(); }
    if (t == 0) *slot = red[0] * scale;
}

// expm via scaling-squaring + Taylor-8 (scaled norm <= 0.66; trunc err ~7e-8 rel)
__device__ __forceinline__ void expm_block(const float* __restrict__ src, float sign,
                                           float* __restrict__ dst, float* __restrict__ dst2,
                                           float* sm, int* shi, int t)
{
    float* As = sm; float* T = sm + 256; float* P = sm + 512; float* rowsum = sm + 768;
    float a = src[t];
    As[t] = a;
    __syncthreads();
    if (t < 16) {
        float rs = 0.f;
        #pragma unroll
        for (int k = 0; k < 16; ++k) rs += fabsf(As[t*16+k]);
        rowsum[t] = rs;
    }
    __syncthreads();
    if (t == 0) {
        float nrm = 0.f;
        for (int i = 0; i < 16; ++i) nrm = fmaxf(nrm, rowsum[i]);
        int s = 0;
        if (nrm > 0.66f) { s = (int)ceilf(log2f(nrm * 1.51515f)); if (s < 0) s = 0; }
        *shi = s;
    }
    __syncthreads();
    int sq = *shi;
    float scale = sign * exp2f((float)(-sq));
    int i = t >> 4, j = t & 15;
    float as = a * scale;
    As[t] = as;
    T[t]  = ((i==j) ? 1.0f : 0.0f) + as;
    P[t]  = as;
    __syncthreads();
    for (int k = 2; k <= 8; ++k) {
        float accv = 0.f;
        #pragma unroll
        for (int m = 0; m < 16; ++m) accv += P[i*16+m]*As[m*16+j];
        float rk = 1.0f/(float)k;
        __syncthreads();
        float term = accv * rk;
        P[t] = term;
        T[t] += term;
        __syncthreads();
    }
    for (int q = 0; q < sq; ++q) {
        float accv = 0.f;
        #pragma unroll
        for (int m = 0; m < 16; ++m) accv += T[i*16+m]*T[m*16+j];
        __syncthreads();
        T[t] = accv;
        __syncthreads();
    }
    dst[t] = T[t];
    if (dst2) dst2[t] = T[t];
}

// gram-tile core (R4-proven): M-fragment = 8 float4 in registers (2 rows/thread),
// N-tile staged in LDS stride-4, read as b128 broadcast (16 lanes/address).
template <bool DO_LOG>
__device__ __forceinline__ float tile_core2(const float* __restrict__ diff,
                                            const float* __restrict__ rinv,
                                            float4* tN4, float* rNs,
                                            int baseM, int baseN, int t)
{
    const float4* gd4 = (const float4*)diff;
    tN4[t]       = gd4[baseN*4 + t];
    tN4[t + 256] = gd4[baseN*4 + 256 + t];
    if (t < 128) rNs[t] = rinv[baseN + t];
    int rp = t >> 2, cg = t & 3;
    int m0 = baseM + rp*2;
    const float4* mp = gd4 + (size_t)m0*4;
    float4 a0 = mp[0], a1 = mp[1], a2 = mp[2], a3 = mp[3];
    float4 b0 = mp[4], b1 = mp[5], b2 = mp[6], b3 = mp[7];
    float ri0 = rinv[m0], ri1 = rinv[m0+1];
    __syncthreads();
    float acc0 = 0.f, acc1 = 0.f;
    #pragma unroll 4
    for (int jj = 0; jj < 32; ++jj) {
        int nj = cg + 4*jj;
        float4 n0 = tN4[nj*4+0], n1 = tN4[nj*4+1], n2 = tN4[nj*4+2], n3 = tN4[nj*4+3];
        float rn = rNs[nj];
        float d0 = a0.x*n0.x + a0.y*n0.y + a0.z*n0.z + a0.w*n0.w
                 + a1.x*n1.x + a1.y*n1.y + a1.z*n1.z + a1.w*n1.w
                 + a2.x*n2.x + a2.y*n2.y + a2.z*n2.z + a2.w*n2.w
                 + a3.x*n3.x + a3.y*n3.y + a3.z*n3.z + a3.w*n3.w;
        float d1 = b0.x*n0.x + b0.y*n0.y + b0.z*n0.z + b0.w*n0.w
                 + b1.x*n1.x + b1.y*n1.y + b1.z*n1.z + b1.w*n1.w
                 + b2.x*n2.x + b2.y*n2.y + b2.z*n2.z + b2.w*n2.w
                 + b3.x*n3.x + b3.y*n3.y + b3.z*n3.z + b3.w*n3.w;
        float s0 = d0 * ri0 * rn;
        float s1 = d1 * ri1 * rn;
        if (DO_LOG) {
            acc0 += __log2f(s0*s0 + 1e-9f);
            acc1 += __log2f(s1*s1 + 1e-9f);
        } else {
            acc0 += s0*s0;
            acc1 += s1*s1;
        }
    }
    return acc0 + acc1;
}

// category reduction helper for the finalizer (256 threads)
__device__ __forceinline__ double cat_reduce(const float* __restrict__ p, int n, int t,
                                             double* dred, bool atom)
{
    double local = 0.0;
    for (int i = t; i < n; i += 256) {
        float x = atom ? atomicAdd(const_cast<float*>(p) + i, 0.0f) : p[i];
        local += (double)x;
    }
    dred[t] = local;
    __syncthreads();
    for (int off = 128; off > 0; off >>= 1) { if (t < off) dred[t] += dred[t+off]; __syncthreads(); }
    double r = dred[0];
    __syncthreads();
    return r;
}

// ---------------- K1: [0,64) prob+ssyms | [64,320) expm(ge) | [320,440) commut ----------------
__global__ void k_stage1(const float* __restrict__ mean, const float* __restrict__ logvar,
                         const float* __restrict__ latent, const float* __restrict__ ge,
                         const float* __restrict__ lin_w, const float* __restrict__ lin_b,
                         const float* __restrict__ gumbel,
                         float* __restrict__ out, float* __restrict__ S_ws,
                         float* __restrict__ syms, float* __restrict__ part,
                         unsigned int* __restrict__ counter)
{
    __shared__ float smem[4864];
    __shared__ int shi;
    int bid = blockIdx.x;
    int t = threadIdx.x;

    if (bid == 0 && t == 0) *counter = 0u;   // stream-ordered: visible before stage3 runs

    if (bid < 64) {
        // ---- prob + ssyms for b = bid ----
        int b = bid;
        float* feat = smem;            // 64
        float* probb = smem + 64;      // 288
        float* red16 = smem + 352;     // 16
        float* wrow = smem + 368;      // 256
        if (t < 64) {
            int k = t; float v;
            if (k < 16)       v = mean[b*16 + k];
            else if (k < 32)  v = expf(0.5f * logvar[b*16 + (k-16)]);
            else if (k < 48)  v = mean[(64+b)*16 + (k-32)];
            else              v = expf(0.5f * mean[(64+b)*16 + (k-48)]);
            feat[k] = v;
        }
        __syncthreads();
        for (int j = t; j < 288; j += 256) {
            float a = lin_b[j];
            const float* wr = lin_w + j*64;
            #pragma unroll
            for (int k = 0; k < 64; ++k) a += feat[k]*wr[k];
            probb[j] = a;
        }
        __syncthreads();
        if (t < 16) {
            int s = t;
            float l0 = probb[2*s], l1 = probb[2*s+1];
            float M = fmaxf(l0,l1);
            float e0 = expf(l0-M), e1 = expf(l1-M);
            float Z = e0+e1;
            float p0 = e0/Z, p1 = e1/Z;
            float M2 = fmaxf(p0,p1);
            float lse = M2 + logf(expf(p0-M2)+expf(p1-M2));
            float ls0 = p0 - lse, ls1 = p1 - lse;
            float z1v = latent[b*16+s], z2v = latent[(64+b)*16+s];
            int tt = (fabsf(z1v - z2v) > 0.2f) ? 1 : 0;
            red16[s] = -(tt ? ls1 : ls0);
            int r = b*16 + s;
            float x0 = (l0 + gumbel[2*r])   * 10000.0f;
            float x1 = (l1 + gumbel[2*r+1]) * 10000.0f;
            float Ma = fmaxf(x0,x1);
            float a0 = expf(x0-Ma), a1 = expf(x1-Ma);
            float Za = a0+a1;
            a0 /= Za; a1 /= Za;
            float sw = ((a0 >= 0.5f) || (a1 > 0.5f)) ? a1 : 0.0f;
            out[O_ATTN + b*272 + s] = sw;
            const float* fl = &probb[32 + s*16];
            float mf = fl[0];
            #pragma unroll
            for (int u = 1; u < 16; ++u) mf = fmaxf(mf, fl[u]);
            float ex[16]; float Zf = 0.f;
            #pragma unroll
            for (int u = 0; u < 16; ++u) { ex[u] = expf(fl[u]-mf); Zf += ex[u]; }
            float rZ = 1.0f/Zf;
            #pragma unroll
            for (int u = 0; u < 16; ++u) {
                float fp = ex[u]*rZ;
                out[O_ATTN + b*272 + 16 + s*16 + u] = fp;
                wrow[s*16 + u] = sw*fp;
            }
        }
        __syncthreads();
        if (t == 0) {
            float s = 0.f;
            for (int i = 0; i < 16; ++i) s += red16[i];
            part[P_SECLOSS + b] = s;
        }
        // ssyms: per-thread element t of each 16x16 matrix
        float Stot = 0.f;
        for (int s = 0; s < 16; ++s) {
            float a = 0.f;
            #pragma unroll
            for (int u = 0; u < 16; ++u)
                a += wrow[s*16+u] * ge[(s*16+u)*256 + t];
            out[O_SUB + b*4096 + s*256 + t] = a;
            Stot += a;
        }
        S_ws[b*256 + t] = Stot;
    } else if (bid < 320) {
        int e = bid - 64;
        expm_block(ge + e*256, 1.0f, syms + e*256, nullptr, smem, &shi, t);
    } else {
        // ---- commut pair ----
        int idx = bid - 320;
        float* G = smem;             // 4096
        float* gA = smem + 4096;     // 256
        float* gB = smem + 4352;     // 256
        float* red = smem + 4608;    // 256
        int a2 = 0, cnt = 15, rem = idx;
        while (rem >= cnt) { rem -= cnt; a2++; cnt--; }
        int b2 = a2 + 1 + rem;
        #pragma unroll
        for (int q = 0; q < 16; ++q) {
            int ii = t + 256*q;
            int k = ii >> 8, x = ii & 255;
            G[ii] = ge[k*16*256 + x];
        }
        gA[t] = ge[a2*256+t];
        gB[t] = ge[b2*256+t];
        __syncthreads();
        int i = t >> 4, j = t & 15;
        float v1 = 0.f, v2 = 0.f;
        #pragma unroll
        for (int k = 0; k < 16; ++k) {
            v1 += gA[i*16+k]*G[k*256 + b2*16 + j];
            v2 += gB[i*16+k]*G[k*256 + a2*16 + j];
        }
        float d = v1 - v2;
        block_store(d*d, red, t, part + P_CPAIR + idx, 2.0f);
    }
}

// ---------------- K2: [0,128) expm(+-S) | [128,384) diff+rinv+sparse ----------------
__global__ void k_stage2(const float* __restrict__ latent, const float* __restrict__ S_ws,
                         const float* __restrict__ syms,
                         float* __restrict__ fwdS, float* __restrict__ invS,
                         float* __restrict__ diff, float* __restrict__ rinv,
                         float* __restrict__ out, float* __restrict__ part)
{
    __shared__ float smem[4608];
    __shared__ int shi;
    int bid = blockIdx.x;
    int t = threadIdx.x;
    if (bid < 64) {
        int b = bid;
        expm_block(S_ws + b*256, 1.0f, fwdS + b*256, out + O_FWD + b*256, smem, &shi, t);
    } else if (bid < 128) {
        int b = bid - 64;
        expm_block(S_ws + b*256, -1.0f, invS + b*256, nullptr, smem, &shi, t);
    } else {
        int e = bid - 128;
        float* zsh = smem;          // 2048
        float* ssh = smem + 2048;   // 256
        float* dsh = smem + 2304;   // 2048
        float* red = smem + 4352;   // 256
        ssh[t] = syms[e*256+t];
        #pragma unroll
        for (int q = 0; q < 8; ++q) zsh[t+256*q] = latent[t+256*q];
        __syncthreads();
        #pragma unroll
        for (int q = 0; q < 8; ++q) {
            int idx = t + 256*q;
            int b = idx >> 4, d = idx & 15;
            float a = 0.f;
            #pragma unroll
            for (int k = 0; k < 16; ++k) a += zsh[b*16+k]*ssh[k*16+d];
            float v = zsh[idx] - a;
            dsh[idx] = v;
            diff[(size_t)e*2048 + idx] = v;
        }
        __syncthreads();
        float pv = 0.f;
        if (t < 128) {
            float sum = 0.f, mx = 0.f;
            #pragma unroll
            for (int d = 0; d < 16; ++d) {
                float v = dsh[t*16+d];
                float v2 = v*v;
                sum += v2; mx = fmaxf(mx, v2);
            }
            float sm2 = sum - mx;
            pv = sm2*sm2;
            rinv[e*128+t] = 1.0f/sqrtf(sum);
        }
        block_store(pv, red, t, part + P_SPARSE + e, 1.0f);
    }
}

// ---------------- K3: [0,2176) parallel | [2176,2296) orth | [2296,2300) tz; last block finalizes ----------------
__global__ void __launch_bounds__(256) k_stage3(const float* __restrict__ diff,
                                                const float* __restrict__ rinv,
                                                const float* __restrict__ latent,
                                                const float* __restrict__ fwdS,
                                                const float* __restrict__ invS,
                                                const int* __restrict__ sec_idx,
                                                float* __restrict__ out,
                                                float* __restrict__ part,
                                                unsigned int* __restrict__ counter)
{
    __shared__ __attribute__((aligned(16))) float4 tN4[512];
    __shared__ float rNs[128];
    __shared__ float redf[256];
    __shared__ double dred[256];
    __shared__ unsigned int lastflag;
    int bid = blockIdx.x;
    int t = threadIdx.x;

    if (bid < 2176) {
        int s = bid / 136;
        int r = bid % 136;
        int tm = 0;
        while (r >= 16 - tm) { r -= 16 - tm; tm++; }
        int tn = tm + r;
        float accf = tile_core2<true>(diff, rinv, tN4, rNs, s*2048 + tm*128, s*2048 + tn*128, t);
        float wt = (tm == tn) ? 1.0f : 2.0f;
        block_store(accf, redf, t, part + P_PAR + bid, wt);
    } else if (bid < 2296) {
        int idx = bid - 2176;
        int sm = 0, cnt = 15, rem = idx;
        while (rem >= cnt) { rem -= cnt; sm++; cnt--; }
        int sn = sm + 1 + rem;
        int em = sm*16 + sec_idx[sm];
        int en = sn*16 + sec_idx[sn];
        float accf = tile_core2<false>(diff, rinv, tN4, rNs, em*128, en*128, t);
        block_store(accf, redf, t, part + P_ORTH + idx, 2.0f);
    } else {
        int g = (bid - 2296)*256 + t;   // 0..1023
        int b = g >> 4, d = g & 15;     // b < 64
        float t1 = 0.f, t2 = 0.f;
        #pragma unroll
        for (int k = 0; k < 16; ++k) {
            t1 += latent[b*16+k]      * fwdS[b*256 + k*16 + d];
            t2 += latent[(64+b)*16+k] * invS[b*256 + k*16 + d];
        }
        out[O_TZ1 + g] = t1;
        out[O_TZ2 + g] = t2;
        float z1v = latent[b*16+d], z2v = latent[(64+b)*16+d];
        float ep = (t2 - z1v)*(t2 - z1v) + (t1 - z2v)*(t1 - z2v);
        block_store(ep, redf, t, part + P_EQUI + (bid - 2296), 1.0f);
    }

    // completion protocol: t0 fences its slot store, bumps counter; last block finalizes
    if (t == 0) {
        __threadfence();
        lastflag = (atomicAdd(counter, 1u) == 2299u) ? 1u : 0u;
    }
    __syncthreads();
    if (lastflag) {
        double s_par  = cat_reduce(part + P_PAR,     2176, t, dred, true);
        double s_orth = cat_reduce(part + P_ORTH,     120, t, dred, true);
        double s_equi = cat_reduce(part + P_EQUI,       4, t, dred, true);
        double s_sec  = cat_reduce(part + P_SECLOSS,   64, t, dred, false);
        double s_spa  = cat_reduce(part + P_SPARSE,   256, t, dred, false);
        double local = 0.0;
        for (int i = t; i < 120; i += 256) local += (double)(120 - i) * (double)part[P_CPAIR + i];
        dred[t] = local;
        __syncthreads();
        for (int off = 128; off > 0; off >>= 1) { if (t < off) dred[t] += dred[t+off]; __syncthreads(); }
        if (t == 0) {
            out[O_COMM]    = (float)(dred[0] / 16777216.0);
            out[O_EQUI]    = (float)(s_equi / 1024.0);
            out[O_ORTH]    = (float)(s_orth / (2048.0*2048.0));
            out[O_PAR]     = (float)(-s_par * 0.6931471805599453 / 67108864.0);
            out[O_SPARSE]  = (float)(s_spa / 32768.0);
            out[O_SECLOSS] = (float)(s_sec / 64.0);
        }
    }
}

extern "C" void kernel_launch(void* const* d_in, const int* in_sizes, int n_in,
                              void* d_out, int out_size, void* d_ws, size_t ws_size,
                              hipStream_t stream)
{
    const float* mean    = (const float*)d_in[0];
    const float* logvar  = (const float*)d_in[1];
    const float* latent  = (const float*)d_in[2];
    const float* ge      = (const float*)d_in[3];
    const float* lin_w   = (const float*)d_in[4];
    const float* lin_b   = (const float*)d_in[5];
    const float* gumbel  = (const float*)d_in[6];
    const int*   sec_idx = (const int*)d_in[7];
    float* out = (float*)d_out;

    char* ws = (char*)d_ws;
    float* part = (float*)ws;                         // 2740 floats of partial slots
    unsigned int* counter = (unsigned int*)(ws + 11264);
    float* fbase = (float*)(ws + 12288);
    float* S_ws = fbase;                    // 16384
    float* syms = fbase + 16384;            // 65536
    float* fwdS = fbase + 81920;            // 16384
    float* invS = fbase + 98304;            // 16384
    float* diff = fbase + 114688;           // 524288
    float* rinv = fbase + 638976;           // 32768

    k_stage1<<<440,  256, 0, stream>>>(mean, logvar, latent, ge, lin_w, lin_b, gumbel,
                                       out, S_ws, syms, part, counter);
    k_stage2<<<384,  256, 0, stream>>>(latent, S_ws, syms, fwdS, invS, diff, rinv, out, part);
    k_stage3<<<2300, 256, 0, stream>>>(diff, rinv, latent, fwdS, invS, sec_idx, out, part, counter);
}

// Round 7
// 120.551 us; speedup vs baseline: 1.2426x; 1.2426x over previous
//
#include <hip/hip_runtime.h>
#include <math.h>

// output offsets (floats)
#define O_TZ1      0
#define O_TZ2      1024
#define O_FWD      2048
#define O_EQUI     18432
#define O_ATTN     18433
#define O_ORTH     35841
#define O_PAR      35842
#define O_COMM     35843
#define O_SPARSE   35844
#define O_SECLOSS  35845
#define O_SUB      35846

// ws layout: acc doubles at 0 (acc0=par, acc1=orth, acc2=equi),
// float slots at +64 bytes: secloss 64, sparse 256, cpair 120
#define P_SECLOSS  0
#define P_SPARSE   64
#define P_CPAIR    320   // total 440 floats

// ---------------- shared device helpers ----------------

__device__ __forceinline__ void block_store(float v, float* red, int t, float* slot, float scale)
{
    red[t] = v;
    __syncthreads();
    for (int off = 128; off > 0; off >>= 1) { if (t < off) red[t] += red[t+off]; __syncthreads(); }
    if (t == 0) *slot = red[0] * scale;
}

__device__ __forceinline__ void block_atomic(float v, float* red, int t, double* dst, float scale)
{
    red[t] = v;
    __syncthreads();
    for (int off = 128; off > 0; off >>= 1) { if (t < off) red[t] += red[t+off]; __syncthreads(); }
    if (t == 0) atomicAdd(dst, (double)(red[0] * scale));
}

// expm via scaling-squaring + Taylor-8 (scaled norm <= 0.66; trunc err ~7e-8 rel)
__device__ __forceinline__ void expm_block(const float* __restrict__ src, float sign,
                                           float* __restrict__ dst, float* __restrict__ dst2,
                                           float* sm, int* shi, int t)
{
    float* As = sm; float* T = sm + 256; float* P = sm + 512; float* rowsum = sm + 768;
    float a = src[t];
    As[t] = a;
    __syncthreads();
    if (t < 16) {
        float rs = 0.f;
        #pragma unroll
        for (int k = 0; k < 16; ++k) rs += fabsf(As[t*16+k]);
        rowsum[t] = rs;
    }
    __syncthreads();
    if (t == 0) {
        float nrm = 0.f;
        for (int i = 0; i < 16; ++i) nrm = fmaxf(nrm, rowsum[i]);
        int s = 0;
        if (nrm > 0.66f) { s = (int)ceilf(log2f(nrm * 1.51515f)); if (s < 0) s = 0; }
        *shi = s;
    }
    __syncthreads();
    int sq = *shi;
    float scale = sign * exp2f((float)(-sq));
    int i = t >> 4, j = t & 15;
    float as = a * scale;
    As[t] = as;
    T[t]  = ((i==j) ? 1.0f : 0.0f) + as;
    P[t]  = as;
    __syncthreads();
    for (int k = 2; k <= 8; ++k) {
        float accv = 0.f;
        #pragma unroll
        for (int m = 0; m < 16; ++m) accv += P[i*16+m]*As[m*16+j];
        float rk = 1.0f/(float)k;
        __syncthreads();
        float term = accv * rk;
        P[t] = term;
        T[t] += term;
        __syncthreads();
    }
    for (int q = 0; q < sq; ++q) {
        float accv = 0.f;
        #pragma unroll
        for (int m = 0; m < 16; ++m) accv += T[i*16+m]*T[m*16+j];
        __syncthreads();
        T[t] = accv;
        __syncthreads();
    }
    dst[t] = T[t];
    if (dst2) dst2[t] = T[t];
}

// gram-tile core (R4-proven): M-fragment = 8 float4 in registers (2 rows/thread),
// N-tile staged in LDS stride-4, read as b128 broadcast (16 lanes/address).
template <bool DO_LOG>
__device__ __forceinline__ float tile_core2(const float* __restrict__ diff,
                                            const float* __restrict__ rinv,
                                            float4* tN4, float* rNs,
                                            int baseM, int baseN, int t)
{
    const float4* gd4 = (const float4*)diff;
    tN4[t]       = gd4[baseN*4 + t];
    tN4[t + 256] = gd4[baseN*4 + 256 + t];
    if (t < 128) rNs[t] = rinv[baseN + t];
    int rp = t >> 2, cg = t & 3;
    int m0 = baseM + rp*2;
    const float4* mp = gd4 + (size_t)m0*4;
    float4 a0 = mp[0], a1 = mp[1], a2 = mp[2], a3 = mp[3];
    float4 b0 = mp[4], b1 = mp[5], b2 = mp[6], b3 = mp[7];
    float ri0 = rinv[m0], ri1 = rinv[m0+1];
    __syncthreads();
    float acc0 = 0.f, acc1 = 0.f;
    #pragma unroll 4
    for (int jj = 0; jj < 32; ++jj) {
        int nj = cg + 4*jj;
        float4 n0 = tN4[nj*4+0], n1 = tN4[nj*4+1], n2 = tN4[nj*4+2], n3 = tN4[nj*4+3];
        float rn = rNs[nj];
        float d0 = a0.x*n0.x + a0.y*n0.y + a0.z*n0.z + a0.w*n0.w
                 + a1.x*n1.x + a1.y*n1.y + a1.z*n1.z + a1.w*n1.w
                 + a2.x*n2.x + a2.y*n2.y + a2.z*n2.z + a2.w*n2.w
                 + a3.x*n3.x + a3.y*n3.y + a3.z*n3.z + a3.w*n3.w;
        float d1 = b0.x*n0.x + b0.y*n0.y + b0.z*n0.z + b0.w*n0.w
                 + b1.x*n1.x + b1.y*n1.y + b1.z*n1.z + b1.w*n1.w
                 + b2.x*n2.x + b2.y*n2.y + b2.z*n2.z + b2.w*n2.w
                 + b3.x*n3.x + b3.y*n3.y + b3.z*n3.z + b3.w*n3.w;
        float s0 = d0 * ri0 * rn;
        float s1 = d1 * ri1 * rn;
        if (DO_LOG) {
            acc0 += __log2f(s0*s0 + 1e-9f);
            acc1 += __log2f(s1*s1 + 1e-9f);
        } else {
            acc0 += s0*s0;
            acc1 += s1*s1;
        }
    }
    return acc0 + acc1;
}

// ---------------- K1: [0,64) prob+ssyms | [64,320) expm(ge) | [320,440) commut ----------------
__global__ void k_stage1(const float* __restrict__ mean, const float* __restrict__ logvar,
                         const float* __restrict__ latent, const float* __restrict__ ge,
                         const float* __restrict__ lin_w, const float* __restrict__ lin_b,
                         const float* __restrict__ gumbel,
                         float* __restrict__ out, float* __restrict__ S_ws,
                         float* __restrict__ syms, float* __restrict__ part,
                         double* __restrict__ acc)
{
    __shared__ float smem[4864];
    __shared__ int shi;
    int bid = blockIdx.x;
    int t = threadIdx.x;

    if (bid == 0 && t == 0) { acc[0] = 0.0; acc[1] = 0.0; acc[2] = 0.0; }  // visible to stage3 via dispatch boundary

    if (bid < 64) {
        // ---- prob + ssyms for b = bid ----
        int b = bid;
        float* feat = smem;            // 64
        float* probb = smem + 64;      // 288
        float* red16 = smem + 352;     // 16
        float* wrow = smem + 368;      // 256
        if (t < 64) {
            int k = t; float v;
            if (k < 16)       v = mean[b*16 + k];
            else if (k < 32)  v = expf(0.5f * logvar[b*16 + (k-16)]);
            else if (k < 48)  v = mean[(64+b)*16 + (k-32)];
            else              v = expf(0.5f * mean[(64+b)*16 + (k-48)]);
            feat[k] = v;
        }
        __syncthreads();
        for (int j = t; j < 288; j += 256) {
            float a = lin_b[j];
            const float* wr = lin_w + j*64;
            #pragma unroll
            for (int k = 0; k < 64; ++k) a += feat[k]*wr[k];
            probb[j] = a;
        }
        __syncthreads();
        if (t < 16) {
            int s = t;
            float l0 = probb[2*s], l1 = probb[2*s+1];
            float M = fmaxf(l0,l1);
            float e0 = expf(l0-M), e1 = expf(l1-M);
            float Z = e0+e1;
            float p0 = e0/Z, p1 = e1/Z;
            float M2 = fmaxf(p0,p1);
            float lse = M2 + logf(expf(p0-M2)+expf(p1-M2));
            float ls0 = p0 - lse, ls1 = p1 - lse;
            float z1v = latent[b*16+s], z2v = latent[(64+b)*16+s];
            int tt = (fabsf(z1v - z2v) > 0.2f) ? 1 : 0;
            red16[s] = -(tt ? ls1 : ls0);
            int r = b*16 + s;
            float x0 = (l0 + gumbel[2*r])   * 10000.0f;
            float x1 = (l1 + gumbel[2*r+1]) * 10000.0f;
            float Ma = fmaxf(x0,x1);
            float a0 = expf(x0-Ma), a1 = expf(x1-Ma);
            float Za = a0+a1;
            a0 /= Za; a1 /= Za;
            float sw = ((a0 >= 0.5f) || (a1 > 0.5f)) ? a1 : 0.0f;
            out[O_ATTN + b*272 + s] = sw;
            const float* fl = &probb[32 + s*16];
            float mf = fl[0];
            #pragma unroll
            for (int u = 1; u < 16; ++u) mf = fmaxf(mf, fl[u]);
            float ex[16]; float Zf = 0.f;
            #pragma unroll
            for (int u = 0; u < 16; ++u) { ex[u] = expf(fl[u]-mf); Zf += ex[u]; }
            float rZ = 1.0f/Zf;
            #pragma unroll
            for (int u = 0; u < 16; ++u) {
                float fp = ex[u]*rZ;
                out[O_ATTN + b*272 + 16 + s*16 + u] = fp;
                wrow[s*16 + u] = sw*fp;
            }
        }
        __syncthreads();
        if (t == 0) {
            float s = 0.f;
            for (int i = 0; i < 16; ++i) s += red16[i];
            part[P_SECLOSS + b] = s;
        }
        // ssyms: per-thread element t of each 16x16 matrix
        float Stot = 0.f;
        for (int s = 0; s < 16; ++s) {
            float a = 0.f;
            #pragma unroll
            for (int u = 0; u < 16; ++u)
                a += wrow[s*16+u] * ge[(s*16+u)*256 + t];
            out[O_SUB + b*4096 + s*256 + t] = a;
            Stot += a;
        }
        S_ws[b*256 + t] = Stot;
    } else if (bid < 320) {
        int e = bid - 64;
        expm_block(ge + e*256, 1.0f, syms + e*256, nullptr, smem, &shi, t);
    } else {
        // ---- commut pair ----
        int idx = bid - 320;
        float* G = smem;             // 4096
        float* gA = smem + 4096;     // 256
        float* gB = smem + 4352;     // 256
        float* red = smem + 4608;    // 256
        int a2 = 0, cnt = 15, rem = idx;
        while (rem >= cnt) { rem -= cnt; a2++; cnt--; }
        int b2 = a2 + 1 + rem;
        #pragma unroll
        for (int q = 0; q < 16; ++q) {
            int ii = t + 256*q;
            int k = ii >> 8, x = ii & 255;
            G[ii] = ge[k*16*256 + x];
        }
        gA[t] = ge[a2*256+t];
        gB[t] = ge[b2*256+t];
        __syncthreads();
        int i = t >> 4, j = t & 15;
        float v1 = 0.f, v2 = 0.f;
        #pragma unroll
        for (int k = 0; k < 16; ++k) {
            v1 += gA[i*16+k]*G[k*256 + b2*16 + j];
            v2 += gB[i*16+k]*G[k*256 + a2*16 + j];
        }
        float d = v1 - v2;
        block_store(d*d, red, t, part + P_CPAIR + idx, 2.0f);
    }
}

// ---------------- K2: [0,128) expm(+-S) | [128,384) diff+rinv+sparse ----------------
__global__ void k_stage2(const float* __restrict__ latent, const float* __restrict__ S_ws,
                         const float* __restrict__ syms,
                         float* __restrict__ fwdS, float* __restrict__ invS,
                         float* __restrict__ diff, float* __restrict__ rinv,
                         float* __restrict__ out, float* __restrict__ part)
{
    __shared__ float smem[4608];
    __shared__ int shi;
    int bid = blockIdx.x;
    int t = threadIdx.x;
    if (bid < 64) {
        int b = bid;
        expm_block(S_ws + b*256, 1.0f, fwdS + b*256, out + O_FWD + b*256, smem, &shi, t);
    } else if (bid < 128) {
        int b = bid - 64;
        expm_block(S_ws + b*256, -1.0f, invS + b*256, nullptr, smem, &shi, t);
    } else {
        int e = bid - 128;
        float* zsh = smem;          // 2048
        float* ssh = smem + 2048;   // 256
        float* dsh = smem + 2304;   // 2048
        float* red = smem + 4352;   // 256
        ssh[t] = syms[e*256+t];
        #pragma unroll
        for (int q = 0; q < 8; ++q) zsh[t+256*q] = latent[t+256*q];
        __syncthreads();
        #pragma unroll
        for (int q = 0; q < 8; ++q) {
            int idx = t + 256*q;
            int b = idx >> 4, d = idx & 15;
            float a = 0.f;
            #pragma unroll
            for (int k = 0; k < 16; ++k) a += zsh[b*16+k]*ssh[k*16+d];
            float v = zsh[idx] - a;
            dsh[idx] = v;
            diff[(size_t)e*2048 + idx] = v;
        }
        __syncthreads();
        float pv = 0.f;
        if (t < 128) {
            float sum = 0.f, mx = 0.f;
            #pragma unroll
            for (int d = 0; d < 16; ++d) {
                float v = dsh[t*16+d];
                float v2 = v*v;
                sum += v2; mx = fmaxf(mx, v2);
            }
            float sm2 = sum - mx;
            pv = sm2*sm2;
            rinv[e*128+t] = 1.0f/sqrtf(sum);
        }
        block_store(pv, red, t, part + P_SPARSE + e, 1.0f);
    }
}

// ---------------- K3: [0,2176) parallel (XCD-swizzled: s = bid&15) | [2176,2296) orth | [2296,2300) tz ----------------
__global__ void __launch_bounds__(256) k_stage3(const float* __restrict__ diff,
                                                const float* __restrict__ rinv,
                                                const float* __restrict__ latent,
                                                const float* __restrict__ fwdS,
                                                const float* __restrict__ invS,
                                                const int* __restrict__ sec_idx,
                                                float* __restrict__ out,
                                                double* __restrict__ acc)
{
    __shared__ __attribute__((aligned(16))) float4 tN4[512];
    __shared__ float rNs[128];
    __shared__ float redf[256];
    int bid = blockIdx.x;
    int t = threadIdx.x;

    if (bid < 2176) {
        // XCD-locality swizzle: sector = bid & 15 (same sector -> same XCD under
        // round-robin dispatch), tile index within sector = bid >> 4 (0..135)
        int s = bid & 15;
        int r = bid >> 4;
        int tm = 0;
        while (r >= 16 - tm) { r -= 16 - tm; tm++; }
        int tn = tm + r;
        float accf = tile_core2<true>(diff, rinv, tN4, rNs, s*2048 + tm*128, s*2048 + tn*128, t);
        float wt = (tm == tn) ? 1.0f : 2.0f;
        block_atomic(accf, redf, t, &acc[0], wt);
    } else if (bid < 2296) {
        int idx = bid - 2176;
        int sm = 0, cnt = 15, rem = idx;
        while (rem >= cnt) { rem -= cnt; sm++; cnt--; }
        int sn = sm + 1 + rem;
        int em = sm*16 + sec_idx[sm];
        int en = sn*16 + sec_idx[sn];
        float accf = tile_core2<false>(diff, rinv, tN4, rNs, em*128, en*128, t);
        block_atomic(accf, redf, t, &acc[1], 2.0f);
    } else {
        int g = (bid - 2296)*256 + t;   // 0..1023
        int b = g >> 4, d = g & 15;     // b < 64
        float t1 = 0.f, t2 = 0.f;
        #pragma unroll
        for (int k = 0; k < 16; ++k) {
            t1 += latent[b*16+k]      * fwdS[b*256 + k*16 + d];
            t2 += latent[(64+b)*16+k] * invS[b*256 + k*16 + d];
        }
        out[O_TZ1 + g] = t1;
        out[O_TZ2 + g] = t2;
        float z1v = latent[b*16+d], z2v = latent[(64+b)*16+d];
        float ep = (t2 - z1v)*(t2 - z1v) + (t1 - z2v)*(t1 - z2v);
        block_atomic(ep, redf, t, &acc[2], 1.0f);
    }
}

// ---------------- K4: final scalar assembly ----------------
__global__ void k_final(const float* __restrict__ part, const double* __restrict__ acc,
                        float* __restrict__ out)
{
    __shared__ double dred[256];
    int t = threadIdx.x;

    // weighted commut sum
    double local = 0.0;
    if (t < 120) local = (double)(120 - t) * (double)part[P_CPAIR + t];
    dred[t] = local;
    __syncthreads();
    for (int off = 128; off > 0; off >>= 1) { if (t < off) dred[t] += dred[t+off]; __syncthreads(); }
    double s_comm = dred[0];
    __syncthreads();

    // secloss (64)
    local = (t < 64) ? (double)part[P_SECLOSS + t] : 0.0;
    dred[t] = local;
    __syncthreads();
    for (int off = 128; off > 0; off >>= 1) { if (t < off) dred[t] += dred[t+off]; __syncthreads(); }
    double s_sec = dred[0];
    __syncthreads();

    // sparse (256)
    dred[t] = (double)part[P_SPARSE + t];
    __syncthreads();
    for (int off = 128; off > 0; off >>= 1) { if (t < off) dred[t] += dred[t+off]; __syncthreads(); }
    double s_spa = dred[0];

    if (t == 0) {
        out[O_COMM]    = (float)(s_comm / 16777216.0);
        out[O_EQUI]    = (float)(acc[2] / 1024.0);
        out[O_ORTH]    = (float)(acc[1] / (2048.0*2048.0));
        out[O_PAR]     = (float)(-acc[0] * 0.6931471805599453 / 67108864.0);
        out[O_SPARSE]  = (float)(s_spa / 32768.0);
        out[O_SECLOSS] = (float)(s_sec / 64.0);
    }
}

extern "C" void kernel_launch(void* const* d_in, const int* in_sizes, int n_in,
                              void* d_out, int out_size, void* d_ws, size_t ws_size,
                              hipStream_t stream)
{
    const float* mean    = (const float*)d_in[0];
    const float* logvar  = (const float*)d_in[1];
    const float* latent  = (const float*)d_in[2];
    const float* ge      = (const float*)d_in[3];
    const float* lin_w   = (const float*)d_in[4];
    const float* lin_b   = (const float*)d_in[5];
    const float* gumbel  = (const float*)d_in[6];
    const int*   sec_idx = (const int*)d_in[7];
    float* out = (float*)d_out;

    char* ws = (char*)d_ws;
    double* acc  = (double*)ws;             // 3 doubles (zeroed by stage1)
    float* part  = (float*)(ws + 64);       // 440 floats of partial slots
    float* fbase = (float*)(ws + 4096);
    float* S_ws = fbase;                    // 16384
    float* syms = fbase + 16384;            // 65536
    float* fwdS = fbase + 81920;            // 16384
    float* invS = fbase + 98304;            // 16384
    float* diff = fbase + 114688;           // 524288
    float* rinv = fbase + 638976;           // 32768

    k_stage1<<<440,  256, 0, stream>>>(mean, logvar, latent, ge, lin_w, lin_b, gumbel,
                                       out, S_ws, syms, part, acc);
    k_stage2<<<384,  256, 0, stream>>>(latent, S_ws, syms, fwdS, invS, diff, rinv, out, part);
    k_stage3<<<2300, 256, 0, stream>>>(diff, rinv, latent, fwdS, invS, sec_idx, out, acc);
    k_final <<<1,    256, 0, stream>>>(part, acc, out);
}

// Round 8
// 115.868 us; speedup vs baseline: 1.2929x; 1.0404x over previous
//
#include <hip/hip_runtime.h>
#include <math.h>

// output offsets (floats)
#define O_TZ1      0
#define O_TZ2      1024
#define O_FWD      2048
#define O_EQUI     18432
#define O_ATTN     18433
#define O_ORTH     35841
#define O_PAR      35842
#define O_COMM     35843
#define O_SPARSE   35844
#define O_SECLOSS  35845
#define O_SUB      35846

// ws float-slot layout (after 64B of doubles): secloss 64, sparse 256, cpair 120
#define P_SECLOSS  0
#define P_SPARSE   64
#define P_CPAIR    320

typedef short s16x8 __attribute__((ext_vector_type(8)));
typedef float f32x4 __attribute__((ext_vector_type(4)));

// ---------------- shared device helpers ----------------

__device__ __forceinline__ void block_store(float v, float* red, int t, float* slot, float scale)
{
    red[t] = v;
    __syncthreads();
    for (int off = 128; off > 0; off >>= 1) { if (t < off) red[t] += red[t+off]; __syncthreads(); }
    if (t == 0) *slot = red[0] * scale;
}

__device__ __forceinline__ void block_atomic(float v, float* red, int t, double* dst, float scale)
{
    red[t] = v;
    __syncthreads();
    for (int off = 128; off > 0; off >>= 1) { if (t < off) red[t] += red[t+off]; __syncthreads(); }
    if (t == 0) atomicAdd(dst, (double)(red[0] * scale));
}

__device__ __forceinline__ unsigned short f2bf(float x)
{
    unsigned int u = __float_as_uint(x);
    u = (u + 0x7FFFu + ((u >> 16) & 1u)) >> 16;   // RNE
    return (unsigned short)u;
}

// expm via scaling-squaring + Taylor-8 (scaled norm <= 0.66; trunc err ~7e-8 rel)
__device__ __forceinline__ void expm_block(const float* __restrict__ src, float sign,
                                           float* __restrict__ dst, float* __restrict__ dst2,
                                           float* sm, int* shi, int t)
{
    float* As = sm; float* T = sm + 256; float* P = sm + 512; float* rowsum = sm + 768;
    float a = src[t];
    As[t] = a;
    __syncthreads();
    if (t < 16) {
        float rs = 0.f;
        #pragma unroll
        for (int k = 0; k < 16; ++k) rs += fabsf(As[t*16+k]);
        rowsum[t] = rs;
    }
    __syncthreads();
    if (t == 0) {
        float nrm = 0.f;
        for (int i = 0; i < 16; ++i) nrm = fmaxf(nrm, rowsum[i]);
        int s = 0;
        if (nrm > 0.66f) { s = (int)ceilf(log2f(nrm * 1.51515f)); if (s < 0) s = 0; }
        *shi = s;
    }
    __syncthreads();
    int sq = *shi;
    float scale = sign * exp2f((float)(-sq));
    int i = t >> 4, j = t & 15;
    float as = a * scale;
    As[t] = as;
    T[t]  = ((i==j) ? 1.0f : 0.0f) + as;
    P[t]  = as;
    __syncthreads();
    for (int k = 2; k <= 8; ++k) {
        float accv = 0.f;
        #pragma unroll
        for (int m = 0; m < 16; ++m) accv += P[i*16+m]*As[m*16+j];
        float rk = 1.0f/(float)k;
        __syncthreads();
        float term = accv * rk;
        P[t] = term;
        T[t] += term;
        __syncthreads();
    }
    for (int q = 0; q < sq; ++q) {
        float accv = 0.f;
        #pragma unroll
        for (int m = 0; m < 16; ++m) accv += T[i*16+m]*T[m*16+j];
        __syncthreads();
        T[t] = accv;
        __syncthreads();
    }
    dst[t] = T[t];
    if (dst2) dst2[t] = T[t];
}

// MFMA gram core: 128x128 tile of the normalized-row gram matrix.
// diffb rows are 16 bf16 (32 B). A/B fragments per m89/m118-verified layouts:
// A[m=lane&15][k=quad*8+j], B[k=quad*8+j][n=lane&15]; k>=16 zero-padded.
// C/D: col=lane&15, row=quad*4+reg.
template <bool DO_LOG>
__device__ __forceinline__ float gram_mfma(const unsigned short* __restrict__ diffb,
                                           int baseM, int baseN, int t)
{
    int lane = t & 63;
    int wave = t >> 6;
    int quad = lane >> 4;
    int col  = lane & 15;
    const s16x8* pb = (const s16x8*)diffb;   // 2 x s16x8 per row
    s16x8 zf = {0,0,0,0,0,0,0,0};
    s16x8 A0 = zf, A1 = zf;
    s16x8 B0 = zf, B1 = zf, B2 = zf, B3 = zf, B4 = zf, B5 = zf, B6 = zf, B7 = zf;
    if (quad < 2) {
        int q = quad;
        A0 = pb[(baseM + wave*32      + col)*2 + q];
        A1 = pb[(baseM + wave*32 + 16 + col)*2 + q];
        B0 = pb[(baseN +   0 + col)*2 + q];
        B1 = pb[(baseN +  16 + col)*2 + q];
        B2 = pb[(baseN +  32 + col)*2 + q];
        B3 = pb[(baseN +  48 + col)*2 + q];
        B4 = pb[(baseN +  64 + col)*2 + q];
        B5 = pb[(baseN +  80 + col)*2 + q];
        B6 = pb[(baseN +  96 + col)*2 + q];
        B7 = pb[(baseN + 112 + col)*2 + q];
    }
    f32x4 cz = {0.f, 0.f, 0.f, 0.f};
    float accf = 0.f;
#define GTILE(AF, BF) { \
    f32x4 c = __builtin_amdgcn_mfma_f32_16x16x32_bf16(AF, BF, cz, 0, 0, 0); \
    _Pragma("unroll") \
    for (int r_ = 0; r_ < 4; ++r_) { \
        float v_ = c[r_]; \
        float x_ = v_*v_ + 1e-9f; \
        accf += DO_LOG ? __log2f(x_) : x_; \
    } }
    GTILE(A0,B0) GTILE(A0,B1) GTILE(A0,B2) GTILE(A0,B3)
    GTILE(A0,B4) GTILE(A0,B5) GTILE(A0,B6) GTILE(A0,B7)
    GTILE(A1,B0) GTILE(A1,B1) GTILE(A1,B2) GTILE(A1,B3)
    GTILE(A1,B4) GTILE(A1,B5) GTILE(A1,B6) GTILE(A1,B7)
#undef GTILE
    return accf;
}

// ---------------- K1: [0,64) prob+ssyms | [64,320) expm(ge) | [320,440) commut ----------------
__global__ void k_stage1(const float* __restrict__ mean, const float* __restrict__ logvar,
                         const float* __restrict__ latent, const float* __restrict__ ge,
                         const float* __restrict__ lin_w, const float* __restrict__ lin_b,
                         const float* __restrict__ gumbel,
                         float* __restrict__ out, float* __restrict__ S_ws,
                         float* __restrict__ syms, float* __restrict__ part,
                         double* __restrict__ acc)
{
    __shared__ float smem[4864];
    __shared__ int shi;
    int bid = blockIdx.x;
    int t = threadIdx.x;

    if (bid == 0 && t == 0) { acc[0] = 0.0; acc[1] = 0.0; acc[2] = 0.0; }

    if (bid < 64) {
        int b = bid;
        float* feat = smem;            // 64
        float* probb = smem + 64;      // 288
        float* red16 = smem + 352;     // 16
        float* wrow = smem + 368;      // 256
        if (t < 64) {
            int k = t; float v;
            if (k < 16)       v = mean[b*16 + k];
            else if (k < 32)  v = expf(0.5f * logvar[b*16 + (k-16)]);
            else if (k < 48)  v = mean[(64+b)*16 + (k-32)];
            else              v = expf(0.5f * mean[(64+b)*16 + (k-48)]);
            feat[k] = v;
        }
        __syncthreads();
        for (int j = t; j < 288; j += 256) {
            float a = lin_b[j];
            const float* wr = lin_w + j*64;
            #pragma unroll
            for (int k = 0; k < 64; ++k) a += feat[k]*wr[k];
            probb[j] = a;
        }
        __syncthreads();
        if (t < 16) {
            int s = t;
            float l0 = probb[2*s], l1 = probb[2*s+1];
            float M = fmaxf(l0,l1);
            float e0 = expf(l0-M), e1 = expf(l1-M);
            float Z = e0+e1;
            float p0 = e0/Z, p1 = e1/Z;
            float M2 = fmaxf(p0,p1);
            float lse = M2 + logf(expf(p0-M2)+expf(p1-M2));
            float ls0 = p0 - lse, ls1 = p1 - lse;
            float z1v = latent[b*16+s], z2v = latent[(64+b)*16+s];
            int tt = (fabsf(z1v - z2v) > 0.2f) ? 1 : 0;
            red16[s] = -(tt ? ls1 : ls0);
            int r = b*16 + s;
            float x0 = (l0 + gumbel[2*r])   * 10000.0f;
            float x1 = (l1 + gumbel[2*r+1]) * 10000.0f;
            float Ma = fmaxf(x0,x1);
            float a0 = expf(x0-Ma), a1 = expf(x1-Ma);
            float Za = a0+a1;
            a0 /= Za; a1 /= Za;
            float sw = ((a0 >= 0.5f) || (a1 > 0.5f)) ? a1 : 0.0f;
            out[O_ATTN + b*272 + s] = sw;
            const float* fl = &probb[32 + s*16];
            float mf = fl[0];
            #pragma unroll
            for (int u = 1; u < 16; ++u) mf = fmaxf(mf, fl[u]);
            float ex[16]; float Zf = 0.f;
            #pragma unroll
            for (int u = 0; u < 16; ++u) { ex[u] = expf(fl[u]-mf); Zf += ex[u]; }
            float rZ = 1.0f/Zf;
            #pragma unroll
            for (int u = 0; u < 16; ++u) {
                float fp = ex[u]*rZ;
                out[O_ATTN + b*272 + 16 + s*16 + u] = fp;
                wrow[s*16 + u] = sw*fp;
            }
        }
        __syncthreads();
        if (t == 0) {
            float s = 0.f;
            for (int i = 0; i < 16; ++i) s += red16[i];
            part[P_SECLOSS + b] = s;
        }
        float Stot = 0.f;
        for (int s = 0; s < 16; ++s) {
            float a = 0.f;
            #pragma unroll
            for (int u = 0; u < 16; ++u)
                a += wrow[s*16+u] * ge[(s*16+u)*256 + t];
            out[O_SUB + b*4096 + s*256 + t] = a;
            Stot += a;
        }
        S_ws[b*256 + t] = Stot;
    } else if (bid < 320) {
        int e = bid - 64;
        expm_block(ge + e*256, 1.0f, syms + e*256, nullptr, smem, &shi, t);
    } else {
        int idx = bid - 320;
        float* G = smem;             // 4096
        float* gA = smem + 4096;     // 256
        float* gB = smem + 4352;     // 256
        float* red = smem + 4608;    // 256
        int a2 = 0, cnt = 15, rem = idx;
        while (rem >= cnt) { rem -= cnt; a2++; cnt--; }
        int b2 = a2 + 1 + rem;
        #pragma unroll
        for (int q = 0; q < 16; ++q) {
            int ii = t + 256*q;
            int k = ii >> 8, x = ii & 255;
            G[ii] = ge[k*16*256 + x];
        }
        gA[t] = ge[a2*256+t];
        gB[t] = ge[b2*256+t];
        __syncthreads();
        int i = t >> 4, j = t & 15;
        float v1 = 0.f, v2 = 0.f;
        #pragma unroll
        for (int k = 0; k < 16; ++k) {
            v1 += gA[i*16+k]*G[k*256 + b2*16 + j];
            v2 += gB[i*16+k]*G[k*256 + a2*16 + j];
        }
        float d = v1 - v2;
        block_store(d*d, red, t, part + P_CPAIR + idx, 2.0f);
    }
}

// ---------------- K2: [0,128) expm(+-S) | [128,384) diff (normalized bf16) + sparse ----------------
__global__ void k_stage2(const float* __restrict__ latent, const float* __restrict__ S_ws,
                         const float* __restrict__ syms,
                         float* __restrict__ fwdS, float* __restrict__ invS,
                         unsigned short* __restrict__ diffb,
                         float* __restrict__ out, float* __restrict__ part)
{
    __shared__ float smem[4608];
    __shared__ int shi;
    int bid = blockIdx.x;
    int t = threadIdx.x;
    if (bid < 64) {
        int b = bid;
        expm_block(S_ws + b*256, 1.0f, fwdS + b*256, out + O_FWD + b*256, smem, &shi, t);
    } else if (bid < 128) {
        int b = bid - 64;
        expm_block(S_ws + b*256, -1.0f, invS + b*256, nullptr, smem, &shi, t);
    } else {
        int e = bid - 128;
        float* zsh = smem;          // 2048
        float* ssh = smem + 2048;   // 256
        float* dsh = smem + 2304;   // 2048
        float* red = smem + 4352;   // 256
        ssh[t] = syms[e*256+t];
        #pragma unroll
        for (int q = 0; q < 8; ++q) zsh[t+256*q] = latent[t+256*q];
        __syncthreads();
        #pragma unroll
        for (int q = 0; q < 8; ++q) {
            int idx = t + 256*q;
            int b = idx >> 4, d = idx & 15;
            float a = 0.f;
            #pragma unroll
            for (int k = 0; k < 16; ++k) a += zsh[b*16+k]*ssh[k*16+d];
            dsh[idx] = zsh[idx] - a;
        }
        __syncthreads();
        float pv = 0.f;
        if (t < 128) {
            float sum = 0.f, mx = 0.f;
            #pragma unroll
            for (int d = 0; d < 16; ++d) {
                float v = dsh[t*16+d];
                float v2 = v*v;
                sum += v2; mx = fmaxf(mx, v2);
            }
            float sm2 = sum - mx;
            pv = sm2*sm2;
            // normalize row, convert to bf16, write 32 B
            float ri = 1.0f / sqrtf(sum);
            unsigned int pk[8];
            #pragma unroll
            for (int d = 0; d < 8; ++d) {
                unsigned short h0 = f2bf(dsh[t*16 + 2*d]     * ri);
                unsigned short h1 = f2bf(dsh[t*16 + 2*d + 1] * ri);
                pk[d] = (unsigned int)h0 | ((unsigned int)h1 << 16);
            }
            uint4* dst = (uint4*)(diffb + (size_t)(e*128 + t)*16);
            dst[0] = make_uint4(pk[0], pk[1], pk[2], pk[3]);
            dst[1] = make_uint4(pk[4], pk[5], pk[6], pk[7]);
        }
        block_store(pv, red, t, part + P_SPARSE + e, 1.0f);
    }
}

// ---------------- K3: [0,2176) parallel (XCD-swizzled) | [2176,2296) orth | [2296,2300) tz ----------------
__global__ void __launch_bounds__(256) k_stage3(const unsigned short* __restrict__ diffb,
                                                const float* __restrict__ latent,
                                                const float* __restrict__ fwdS,
                                                const float* __restrict__ invS,
                                                const int* __restrict__ sec_idx,
                                                float* __restrict__ out,
                                                double* __restrict__ acc)
{
    __shared__ float redf[256];
    int bid = blockIdx.x;
    int t = threadIdx.x;

    if (bid < 2176) {
        int s = bid & 15;         // XCD-locality swizzle
        int r = bid >> 4;         // 0..135
        int tm = 0;
        while (r >= 16 - tm) { r -= 16 - tm; tm++; }
        int tn = tm + r;
        float accf = gram_mfma<true>(diffb, s*2048 + tm*128, s*2048 + tn*128, t);
        float wt = (tm == tn) ? 1.0f : 2.0f;
        block_atomic(accf, redf, t, &acc[0], wt);
    } else if (bid < 2296) {
        int idx = bid - 2176;
        int sm = 0, cnt = 15, rem = idx;
        while (rem >= cnt) { rem -= cnt; sm++; cnt--; }
        int sn = sm + 1 + rem;
        int em = sm*16 + sec_idx[sm];
        int en = sn*16 + sec_idx[sn];
        float accf = gram_mfma<false>(diffb, em*128, en*128, t);
        block_atomic(accf, redf, t, &acc[1], 2.0f);
    } else {
        int g = (bid - 2296)*256 + t;   // 0..1023
        int b = g >> 4, d = g & 15;     // b < 64
        float t1 = 0.f, t2 = 0.f;
        #pragma unroll
        for (int k = 0; k < 16; ++k) {
            t1 += latent[b*16+k]      * fwdS[b*256 + k*16 + d];
            t2 += latent[(64+b)*16+k] * invS[b*256 + k*16 + d];
        }
        out[O_TZ1 + g] = t1;
        out[O_TZ2 + g] = t2;
        float z1v = latent[b*16+d], z2v = latent[(64+b)*16+d];
        float ep = (t2 - z1v)*(t2 - z1v) + (t1 - z2v)*(t1 - z2v);
        block_atomic(ep, redf, t, &acc[2], 1.0f);
    }
}

// ---------------- K4: final scalar assembly ----------------
__global__ void k_final(const float* __restrict__ part, const double* __restrict__ acc,
                        float* __restrict__ out)
{
    __shared__ double dred[256];
    int t = threadIdx.x;

    double local = 0.0;
    if (t < 120) local = (double)(120 - t) * (double)part[P_CPAIR + t];
    dred[t] = local;
    __syncthreads();
    for (int off = 128; off > 0; off >>= 1) { if (t < off) dred[t] += dred[t+off]; __syncthreads(); }
    double s_comm = dred[0];
    __syncthreads();

    local = (t < 64) ? (double)part[P_SECLOSS + t] : 0.0;
    dred[t] = local;
    __syncthreads();
    for (int off = 128; off > 0; off >>= 1) { if (t < off) dred[t] += dred[t+off]; __syncthreads(); }
    double s_sec = dred[0];
    __syncthreads();

    dred[t] = (double)part[P_SPARSE + t];
    __syncthreads();
    for (int off = 128; off > 0; off >>= 1) { if (t < off) dred[t] += dred[t+off]; __syncthreads(); }
    double s_spa = dred[0];

    if (t == 0) {
        out[O_COMM]    = (float)(s_comm / 16777216.0);
        out[O_EQUI]    = (float)(acc[2] / 1024.0);
        out[O_ORTH]    = (float)(acc[1] / (2048.0*2048.0));
        out[O_PAR]     = (float)(-acc[0] * 0.6931471805599453 / 67108864.0);
        out[O_SPARSE]  = (float)(s_spa / 32768.0);
        out[O_SECLOSS] = (float)(s_sec / 64.0);
    }
}

extern "C" void kernel_launch(void* const* d_in, const int* in_sizes, int n_in,
                              void* d_out, int out_size, void* d_ws, size_t ws_size,
                              hipStream_t stream)
{
    const float* mean    = (const float*)d_in[0];
    const float* logvar  = (const float*)d_in[1];
    const float* latent  = (const float*)d_in[2];
    const float* ge      = (const float*)d_in[3];
    const float* lin_w   = (const float*)d_in[4];
    const float* lin_b   = (const float*)d_in[5];
    const float* gumbel  = (const float*)d_in[6];
    const int*   sec_idx = (const int*)d_in[7];
    float* out = (float*)d_out;

    char* ws = (char*)d_ws;
    double* acc  = (double*)ws;             // 3 doubles (zeroed by stage1)
    float* part  = (float*)(ws + 64);       // 440 floats of partial slots
    float* fbase = (float*)(ws + 4096);
    float* S_ws = fbase;                    // 16384 floats
    float* syms = fbase + 16384;            // 65536
    float* fwdS = fbase + 81920;            // 16384
    float* invS = fbase + 98304;            // 16384
    unsigned short* diffb = (unsigned short*)(fbase + 114688);   // 32768 rows x 16 bf16 = 1 MB

    k_stage1<<<440,  256, 0, stream>>>(mean, logvar, latent, ge, lin_w, lin_b, gumbel,
                                       out, S_ws, syms, part, acc);
    k_stage2<<<384,  256, 0, stream>>>(latent, S_ws, syms, fwdS, invS, diffb, out, part);
    k_stage3<<<2300, 256, 0, stream>>>(diffb, latent, fwdS, invS, sec_idx, out, acc);
    k_final <<<1,    256, 0, stream>>>(part, acc, out);
}

// Round 10
// 94.463 us; speedup vs baseline: 1.5858x; 1.2266x over previous
//
#include <hip/hip_runtime.h>
#include <math.h>

// output offsets (floats)
#define O_TZ1      0
#define O_TZ2      1024
#define O_FWD      2048
#define O_EQUI     18432
#define O_ATTN     18433
#define O_ORTH     35841
#define O_PAR      35842
#define O_COMM     35843
#define O_SPARSE   35844
#define O_SECLOSS  35845
#define O_SUB      35846

// partial-slot layout (floats at ws base) — every slot written unconditionally each launch
#define P_SECLOSS  0      // 64
#define P_SPARSE   64     // 256
#define P_CPAIR    320    // 120
#define P_EQUI     440    // 64
#define P_PAR      504    // 2176
#define P_ORTH     2680   // 120  (total 2800)

typedef short s16x8 __attribute__((ext_vector_type(8)));
typedef float f32x4 __attribute__((ext_vector_type(4)));

__device__ __forceinline__ void block_store(float v, float* red, int t, float* slot, float scale)
{
    red[t] = v;
    __syncthreads();
    for (int off = 128; off > 0; off >>= 1) { if (t < off) red[t] += red[t+off]; __syncthreads(); }
    if (t == 0) *slot = red[0] * scale;
}

__device__ __forceinline__ unsigned short f2bf(float x)
{
    unsigned int u = __float_as_uint(x);
    u = (u + 0x7FFFu + ((u >> 16) & 1u)) >> 16;   // RNE
    return (unsigned short)u;
}

// expm via scaling-squaring + Taylor-8; result left in sm[256..511] ("T").
// sm needs >= 784 floats: As 0..255, T 256..511, P 512..767, rowsum 768..783.
__device__ __forceinline__ void expm_core(const float* __restrict__ src, float sign,
                                          float* sm, int* shi, int t)
{
    float* As = sm; float* T = sm + 256; float* P = sm + 512; float* rowsum = sm + 768;
    float a = src[t];
    As[t] = a;
    __syncthreads();
    if (t < 16) {
        float rs = 0.f;
        #pragma unroll
        for (int k = 0; k < 16; ++k) rs += fabsf(As[t*16+k]);
        rowsum[t] = rs;
    }
    __syncthreads();
    if (t == 0) {
        float nrm = 0.f;
        for (int i = 0; i < 16; ++i) nrm = fmaxf(nrm, rowsum[i]);
        int s = 0;
        if (nrm > 0.66f) { s = (int)ceilf(log2f(nrm * 1.51515f)); if (s < 0) s = 0; }
        *shi = s;
    }
    __syncthreads();
    int sq = *shi;
    float scale = sign * exp2f((float)(-sq));
    int i = t >> 4, j = t & 15;
    float as = a * scale;
    As[t] = as;
    T[t]  = ((i==j) ? 1.0f : 0.0f) + as;
    P[t]  = as;
    __syncthreads();
    for (int k = 2; k <= 8; ++k) {
        float accv = 0.f;
        #pragma unroll
        for (int m = 0; m < 16; ++m) accv += P[i*16+m]*As[m*16+j];
        float rk = 1.0f/(float)k;
        __syncthreads();
        float term = accv * rk;
        P[t] = term;
        T[t] += term;
        __syncthreads();
    }
    for (int q = 0; q < sq; ++q) {
        float accv = 0.f;
        #pragma unroll
        for (int m = 0; m < 16; ++m) accv += T[i*16+m]*T[m*16+j];
        __syncthreads();
        T[t] = accv;
        __syncthreads();
    }
}

// MFMA gram core (R8-proven): 128x128 tile of normalized-row gram.
// A[m=lane&15][k=quad*8+j], B[k=quad*8+j][n=lane&15]; k>=16 zero-padded.
template <bool DO_LOG>
__device__ __forceinline__ float gram_mfma(const unsigned short* __restrict__ diffb,
                                           int baseM, int baseN, int t)
{
    int lane = t & 63;
    int wave = t >> 6;
    int quad = lane >> 4;
    int col  = lane & 15;
    const s16x8* pb = (const s16x8*)diffb;   // 2 x s16x8 per row
    s16x8 zf = {0,0,0,0,0,0,0,0};
    s16x8 A0 = zf, A1 = zf;
    s16x8 B0 = zf, B1 = zf, B2 = zf, B3 = zf, B4 = zf, B5 = zf, B6 = zf, B7 = zf;
    if (quad < 2) {
        int q = quad;
        A0 = pb[(baseM + wave*32      + col)*2 + q];
        A1 = pb[(baseM + wave*32 + 16 + col)*2 + q];
        B0 = pb[(baseN +   0 + col)*2 + q];
        B1 = pb[(baseN +  16 + col)*2 + q];
        B2 = pb[(baseN +  32 + col)*2 + q];
        B3 = pb[(baseN +  48 + col)*2 + q];
        B4 = pb[(baseN +  64 + col)*2 + q];
        B5 = pb[(baseN +  80 + col)*2 + q];
        B6 = pb[(baseN +  96 + col)*2 + q];
        B7 = pb[(baseN + 112 + col)*2 + q];
    }
    f32x4 cz = {0.f, 0.f, 0.f, 0.f};
    float accf = 0.f;
#define GTILE(AF, BF) { \
    f32x4 c = __builtin_amdgcn_mfma_f32_16x16x32_bf16(AF, BF, cz, 0, 0, 0); \
    _Pragma("unroll") \
    for (int r_ = 0; r_ < 4; ++r_) { \
        float v_ = c[r_]; \
        float x_ = v_*v_ + 1e-9f; \
        accf += DO_LOG ? __log2f(x_) : x_; \
    } }
    GTILE(A0,B0) GTILE(A0,B1) GTILE(A0,B2) GTILE(A0,B3)
    GTILE(A0,B4) GTILE(A0,B5) GTILE(A0,B6) GTILE(A0,B7)
    GTILE(A1,B0) GTILE(A1,B1) GTILE(A1,B2) GTILE(A1,B3)
    GTILE(A1,B4) GTILE(A1,B5) GTILE(A1,B6) GTILE(A1,B7)
#undef GTILE
    return accf;
}

// ---------------- K1: [0,64) prob+ssyms | [64,320) expm(ge)+diff+bf16+sparse | [320,440) commut ----------------
__global__ void k_stage1(const float* __restrict__ mean, const float* __restrict__ logvar,
                         const float* __restrict__ latent, const float* __restrict__ ge,
                         const float* __restrict__ lin_w, const float* __restrict__ lin_b,
                         const float* __restrict__ gumbel,
                         float* __restrict__ out, float* __restrict__ S_ws,
                         unsigned short* __restrict__ diffb, float* __restrict__ part)
{
    __shared__ float smem[4864];
    __shared__ int shi;
    int bid = blockIdx.x;
    int t = threadIdx.x;

    if (bid < 64) {
        int b = bid;
        float* feat = smem;            // 64
        float* probb = smem + 64;      // 288
        float* red16 = smem + 352;     // 16
        float* wrow = smem + 368;      // 256
        if (t < 64) {
            int k = t; float v;
            if (k < 16)       v = mean[b*16 + k];
            else if (k < 32)  v = expf(0.5f * logvar[b*16 + (k-16)]);
            else if (k < 48)  v = mean[(64+b)*16 + (k-32)];
            else              v = expf(0.5f * mean[(64+b)*16 + (k-48)]);
            feat[k] = v;
        }
        __syncthreads();
        for (int j = t; j < 288; j += 256) {
            float a = lin_b[j];
            const float* wr = lin_w + j*64;
            #pragma unroll
            for (int k = 0; k < 64; ++k) a += feat[k]*wr[k];
            probb[j] = a;
        }
        __syncthreads();
        if (t < 16) {
            int s = t;
            float l0 = probb[2*s], l1 = probb[2*s+1];
            float M = fmaxf(l0,l1);
            float e0 = expf(l0-M), e1 = expf(l1-M);
            float Z = e0+e1;
            float p0 = e0/Z, p1 = e1/Z;
            float M2 = fmaxf(p0,p1);
            float lse = M2 + logf(expf(p0-M2)+expf(p1-M2));
            float ls0 = p0 - lse, ls1 = p1 - lse;
            float z1v = latent[b*16+s], z2v = latent[(64+b)*16+s];
            int tt = (fabsf(z1v - z2v) > 0.2f) ? 1 : 0;
            red16[s] = -(tt ? ls1 : ls0);
            int r = b*16 + s;
            float x0 = (l0 + gumbel[2*r])   * 10000.0f;
            float x1 = (l1 + gumbel[2*r+1]) * 10000.0f;
            float Ma = fmaxf(x0,x1);
            float a0 = expf(x0-Ma), a1 = expf(x1-Ma);
            float Za = a0+a1;
            a0 /= Za; a1 /= Za;
            float sw = ((a0 >= 0.5f) || (a1 > 0.5f)) ? a1 : 0.0f;
            out[O_ATTN + b*272 + s] = sw;
            const float* fl = &probb[32 + s*16];
            float mf = fl[0];
            #pragma unroll
            for (int u = 1; u < 16; ++u) mf = fmaxf(mf, fl[u]);
            float ex[16]; float Zf = 0.f;
            #pragma unroll
            for (int u = 0; u < 16; ++u) { ex[u] = expf(fl[u]-mf); Zf += ex[u]; }
            float rZ = 1.0f/Zf;
            #pragma unroll
            for (int u = 0; u < 16; ++u) {
                float fp = ex[u]*rZ;
                out[O_ATTN + b*272 + 16 + s*16 + u] = fp;
                wrow[s*16 + u] = sw*fp;
            }
        }
        __syncthreads();
        if (t == 0) {
            float s = 0.f;
            for (int i = 0; i < 16; ++i) s += red16[i];
            part[P_SECLOSS + b] = s;
        }
        float Stot = 0.f;
        for (int s = 0; s < 16; ++s) {
            float a = 0.f;
            #pragma unroll
            for (int u = 0; u < 16; ++u)
                a += wrow[s*16+u] * ge[(s*16+u)*256 + t];
            out[O_SUB + b*4096 + s*256 + t] = a;
            Stot += a;
        }
        S_ws[b*256 + t] = Stot;
    } else if (bid < 320) {
        // ---- fused expm(ge[e]) + diff + normalize + bf16 + sparse ----
        int e = bid - 64;
        float* zsh = smem + 784;      // 2048
        float* red = smem + 2832;     // 256
        #pragma unroll
        for (int q = 0; q < 8; ++q) zsh[t+256*q] = latent[t+256*q];
        expm_core(ge + e*256, 1.0f, smem, &shi, t);   // T = smem+256; its syncs cover zsh
        const float* T = smem + 256;
        float pv = 0.f;
        if (t < 128) {
            float zr[16];
            #pragma unroll
            for (int k = 0; k < 16; ++k) zr[k] = zsh[t*16+k];
            float dv[16];
            float sum = 0.f, mx = 0.f;
            #pragma unroll
            for (int d = 0; d < 16; ++d) {
                float a = 0.f;
                #pragma unroll
                for (int k = 0; k < 16; ++k) a += zr[k]*T[k*16+d];
                float v = zr[d] - a;
                dv[d] = v;
                float v2 = v*v;
                sum += v2; mx = fmaxf(mx, v2);
            }
            float sm2 = sum - mx;
            pv = sm2*sm2;
            float ri = 1.0f / sqrtf(sum);
            unsigned int pk[8];
            #pragma unroll
            for (int d = 0; d < 8; ++d) {
                unsigned short h0 = f2bf(dv[2*d]   * ri);
                unsigned short h1 = f2bf(dv[2*d+1] * ri);
                pk[d] = (unsigned int)h0 | ((unsigned int)h1 << 16);
            }
            uint4* dst = (uint4*)(diffb + (size_t)(e*128 + t)*16);
            dst[0] = make_uint4(pk[0], pk[1], pk[2], pk[3]);
            dst[1] = make_uint4(pk[4], pk[5], pk[6], pk[7]);
        }
        block_store(pv, red, t, part + P_SPARSE + e, 1.0f);
    } else {
        int idx = bid - 320;
        float* G = smem;             // 4096
        float* gA = smem + 4096;     // 256
        float* gB = smem + 4352;     // 256
        float* red = smem + 4608;    // 256
        int a2 = 0, cnt = 15, rem = idx;
        while (rem >= cnt) { rem -= cnt; a2++; cnt--; }
        int b2 = a2 + 1 + rem;
        #pragma unroll
        for (int q = 0; q < 16; ++q) {
            int ii = t + 256*q;
            int k = ii >> 8, x = ii & 255;
            G[ii] = ge[k*16*256 + x];
        }
        gA[t] = ge[a2*256+t];
        gB[t] = ge[b2*256+t];
        __syncthreads();
        int i = t >> 4, j = t & 15;
        float v1 = 0.f, v2 = 0.f;
        #pragma unroll
        for (int k = 0; k < 16; ++k) {
            v1 += gA[i*16+k]*G[k*256 + b2*16 + j];
            v2 += gB[i*16+k]*G[k*256 + a2*16 + j];
        }
        float d = v1 - v2;
        block_store(d*d, red, t, part + P_CPAIR + idx, 2.0f);
    }
}

// ---------------- K2: [0,64) expm(+-S)+fwd+tz+equi | [64,2240) parallel | [2240,2360) orth ----------------
__global__ void __launch_bounds__(256) k_stage2(const float* __restrict__ latent,
                                                const float* __restrict__ S_ws,
                                                const unsigned short* __restrict__ diffb,
                                                const int* __restrict__ sec_idx,
                                                float* __restrict__ out,
                                                float* __restrict__ part)
{
    __shared__ float smem[1040];   // expm scratch 784 + red 256
    __shared__ int shi;
    int bid = blockIdx.x;
    int t = threadIdx.x;
    float* red = smem + 784;

    if (bid < 64) {
        int b = bid;
        expm_core(S_ws + b*256, 1.0f, smem, &shi, t);
        const float* T = smem + 256;
        out[O_FWD + b*256 + t] = T[t];
        float t1 = 0.f, z1d = 0.f, z2d = 0.f;
        if (t < 16) {
            int d = t;
            #pragma unroll
            for (int k = 0; k < 16; ++k) t1 += latent[b*16+k] * T[k*16+d];
            out[O_TZ1 + b*16 + d] = t1;
            z1d = latent[b*16+d];
            z2d = latent[(64+b)*16+d];
        }
        expm_core(S_ws + b*256, -1.0f, smem, &shi, t);   // internal syncs order prior T reads
        float t2 = 0.f, ep = 0.f;
        if (t < 16) {
            int d = t;
            #pragma unroll
            for (int k = 0; k < 16; ++k) t2 += latent[(64+b)*16+k] * T[k*16+d];
            out[O_TZ2 + b*16 + d] = t2;
            ep = (t2 - z1d)*(t2 - z1d) + (t1 - z2d)*(t1 - z2d);
        }
        block_store(ep, red, t, part + P_EQUI + b, 1.0f);
    } else if (bid < 2240) {
        int tile = bid - 64;
        int s = tile & 15;        // XCD-locality swizzle
        int r = tile >> 4;        // 0..135
        int tm = 0;
        while (r >= 16 - tm) { r -= 16 - tm; tm++; }
        int tn = tm + r;
        float accf = gram_mfma<true>(diffb, s*2048 + tm*128, s*2048 + tn*128, t);
        float wt = (tm == tn) ? 1.0f : 2.0f;
        block_store(accf, red, t, part + P_PAR + tile, wt);
    } else {
        int idx = bid - 2240;
        int sm = 0, cnt = 15, rem = idx;
        while (rem >= cnt) { rem -= cnt; sm++; cnt--; }
        int sn = sm + 1 + rem;
        int em = sm*16 + sec_idx[sm];
        int en = sn*16 + sec_idx[sn];
        float accf = gram_mfma<false>(diffb, em*128, en*128, t);
        block_store(accf, red, t, part + P_ORTH + idx, 2.0f);
    }
}

// ---------------- K3: final scalar assembly (reads prior-dispatch plain stores) ----------------
__global__ void k_final(const float* __restrict__ part, float* __restrict__ out)
{
    __shared__ double dred[256];
    int t = threadIdx.x;

    double local = 0.0;
    for (int i = t; i < 2176; i += 256) local += (double)part[P_PAR + i];
    dred[t] = local;
    __syncthreads();
    for (int off = 128; off > 0; off >>= 1) { if (t < off) dred[t] += dred[t+off]; __syncthreads(); }
    double s_par = dred[0];
    __syncthreads();

    local = 0.0;
    if (t < 120) local += (double)part[P_ORTH + t];
    dred[t] = local;
    __syncthreads();
    for (int off = 128; off > 0; off >>= 1) { if (t < off) dred[t] += dred[t+off]; __syncthreads(); }
    double s_orth = dred[0];
    __syncthreads();

    local = 0.0;
    if (t < 64) local += (double)part[P_EQUI + t];
    if (t < 64) local += 0.0;
    dred[t] = local;
    __syncthreads();
    for (int off = 128; off > 0; off >>= 1) { if (t < off) dred[t] += dred[t+off]; __syncthreads(); }
    double s_equi = dred[0];
    __syncthreads();

    local = (t < 64) ? (double)part[P_SECLOSS + t] : 0.0;
    dred[t] = local;
    __syncthreads();
    for (int off = 128; off > 0; off >>= 1) { if (t < off) dred[t] += dred[t+off]; __syncthreads(); }
    double s_sec = dred[0];
    __syncthreads();

    dred[t] = (double)part[P_SPARSE + t];
    __syncthreads();
    for (int off = 128; off > 0; off >>= 1) { if (t < off) dred[t] += dred[t+off]; __syncthreads(); }
    double s_spa = dred[0];
    __syncthreads();

    local = 0.0;
    if (t < 120) local = (double)(120 - t) * (double)part[P_CPAIR + t];
    dred[t] = local;
    __syncthreads();
    for (int off = 128; off > 0; off >>= 1) { if (t < off) dred[t] += dred[t+off]; __syncthreads(); }

    if (t == 0) {
        out[O_COMM]    = (float)(dred[0] / 16777216.0);
        out[O_EQUI]    = (float)(s_equi / 1024.0);
        out[O_ORTH]    = (float)(s_orth / (2048.0*2048.0));
        out[O_PAR]     = (float)(-s_par * 0.6931471805599453 / 67108864.0);
        out[O_SPARSE]  = (float)(s_spa / 32768.0);
        out[O_SECLOSS] = (float)(s_sec / 64.0);
    }
}

extern "C" void kernel_launch(void* const* d_in, const int* in_sizes, int n_in,
                              void* d_out, int out_size, void* d_ws, size_t ws_size,
                              hipStream_t stream)
{
    const float* mean    = (const float*)d_in[0];
    const float* logvar  = (const float*)d_in[1];
    const float* latent  = (const float*)d_in[2];
    const float* ge      = (const float*)d_in[3];
    const float* lin_w   = (const float*)d_in[4];
    const float* lin_b   = (const float*)d_in[5];
    const float* gumbel  = (const float*)d_in[6];
    const int*   sec_idx = (const int*)d_in[7];
    float* out = (float*)d_out;

    char* ws = (char*)d_ws;
    float* part = (float*)ws;                               // 2800 floats (all written each launch)
    float* S_ws = (float*)(ws + 16384);                     // 16384 floats
    unsigned short* diffb = (unsigned short*)(ws + 81920);  // 32768 rows x 16 bf16 = 1 MB

    k_stage1<<<440,  256, 0, stream>>>(mean, logvar, latent, ge, lin_w, lin_b, gumbel,
                                       out, S_ws, diffb, part);
    k_stage2<<<2360, 256, 0, stream>>>(latent, S_ws, diffb, sec_idx, out, part);
    k_final <<<1,    256, 0, stream>>>(part, out);
}